// Round 1
// baseline (3006.414 us; speedup 1.0000x reference)
//
#include <hip/hip_runtime.h>
#include <hip/hip_bf16.h>

// GRU stack (Keras reset_after, gates z,r,h) + dense + softmax on MI355X.
// B=256 T=15 L=6 U=1000 E=1024 V=32000.
// Strategy: bf16 MFMA 16x16x32 everywhere; anti-diagonal wavefront batching
// (20 sequential steps instead of 90); weights pre-transposed to K-major bf16
// with gate blocks padded 1000->1024 (tile-aligned, pads stay zero).

#define B_ 256
#define T_ 15
#define L_ 6
#define U_ 1000
#define UP 1024
#define E_ 1024
#define V_ 32000
#define G3 3072                 // 3 * UP (z | r | h gate blocks)
#define MATSZ ((size_t)G3 * UP) // elems per converted weight matrix
#define DK 6000
#define DKP 6016

typedef __attribute__((ext_vector_type(8))) short short8; // 8 bf16 = 4 VGPRs
typedef __attribute__((ext_vector_type(4))) float f32x4;

static __device__ __forceinline__ unsigned short f2bf(float f) {
    __hip_bfloat16 h = __float2bfloat16(f);
    return *(unsigned short*)&h;
}

// ---------------------------------------------------------------------------
// Weight conversion: 17 matrices -> bf16, K-major [3072 n][1024 k], zero-padded.
// m 0..5  = WX[l]  (x part: kernel0 / kernels_rest rows 0..1023, Kvalid=1024)
// m 6..10 = WP[l=1..5] (skip part: kernels_rest rows 1024..2023, Kvalid=1000)
// m 11..16= WR[l]  (recurrent: rec_kernels, Kvalid=1000)
// Column map: src col g*1000+u -> dst row g*1024+u (u<1000), pad rows zero.
__global__ void conv_weights(const float* __restrict__ k0w,
                             const float* __restrict__ krest,
                             const float* __restrict__ reck,
                             unsigned short* __restrict__ wts) {
    __shared__ unsigned short Ts[64 * 72];
    int m = blockIdx.z;
    int kt = blockIdx.y * 64;   // k-tile origin
    int n0 = blockIdx.x * 64;   // dst-row (= src col block) origin
    const float* src;
    int kvalid;
    if (m < 6)       { src = (m == 0) ? k0w : krest + (size_t)(m - 1) * 2024 * 3000; kvalid = 1024; }
    else if (m < 11) { src = krest + (size_t)(m - 6) * 2024 * 3000 + (size_t)1024 * 3000; kvalid = 1000; }
    else             { src = reck + (size_t)(m - 11) * 1000 * 3000; kvalid = 1000; }
    int g = n0 >> 10, u0 = n0 & 1023;
    int tid = threadIdx.x;
    for (int i = 0; i < 16; ++i) {
        int c = i * 256 + tid;
        int kk = c >> 6, nn = c & 63;
        float v = 0.f;
        int gk = kt + kk, gu = u0 + nn;
        if (gk < kvalid && gu < 1000) v = src[(size_t)gk * 3000 + g * 1000 + gu];
        Ts[kk * 72 + nn] = f2bf(v);
    }
    __syncthreads();
    unsigned short* dst = wts + (size_t)m * MATSZ;
    for (int i = 0; i < 2; ++i) {
        int c = i * 256 + tid;           // 512 chunks of 8 bf16
        int n = c >> 3, kc = (c & 7) * 8;
        unsigned short tmp[8];
        for (int j = 0; j < 8; ++j) tmp[j] = Ts[(kc + j) * 72 + n];
        *(uint4*)(dst + (size_t)(n0 + n) * UP + kt + kc) = *(uint4*)tmp;
    }
}

// Embedding gather -> bf16, rows r = t*256 + b, [3840][1024]
__global__ void emb_gather(const int* __restrict__ tokens,
                           const float* __restrict__ emb,
                           unsigned short* __restrict__ xbf) {
    int r = blockIdx.x;
    int t = r >> 8, b = r & 255;
    int tok = tokens[b * T_ + t];
    int e0 = threadIdx.x * 4;
    float4 v = *(const float4*)(emb + (size_t)tok * E_ + e0);
    ushort4 o;
    o.x = f2bf(v.x); o.y = f2bf(v.y); o.z = f2bf(v.z); o.w = f2bf(v.w);
    *(ushort4*)(xbf + (size_t)r * E_ + e0) = o;
}

// Hidden state init from init_states [L][B][1000] -> padded [L][B][1024] f32+bf16
__global__ void h_init(const float* __restrict__ init,
                       float* __restrict__ h32,
                       unsigned short* __restrict__ hbf) {
    int f = (blockIdx.x * 256 + threadIdx.x) * 4; // 1536 blocks
    int u = f & 1023, idx = f >> 10;
    int b = idx & 255, l = idx >> 8;
    const float* s = init + (size_t)(l * 256 + b) * 1000;
    float vv[4];
    ushort4 hb;
    for (int j = 0; j < 4; ++j) vv[j] = (u + j < 1000) ? s[u + j] : 0.f;
    hb.x = f2bf(vv[0]); hb.y = f2bf(vv[1]); hb.z = f2bf(vv[2]); hb.w = f2bf(vv[3]);
    size_t o = (size_t)(l * 256 + b) * UP + u;
    *(float4*)(h32 + o) = make_float4(vv[0], vv[1], vv[2], vv[3]);
    *(ushort4*)(hbf + o) = hb;
}

// ---------------------------------------------------------------------------
// Batched GEMM: C[256][3072] f32 = A[256][1024] bf16 @ B (K-major [3072][1024] bf16)
// 128x128 tile, BK=64, 4 waves, 16x16x32 MFMA. grid (2, 24, nmm).
struct MMDesc {
    const unsigned short* A[18];
    const unsigned short* Bm[18];
    float* C[18];
};

__launch_bounds__(256, 2)
__global__ void gemm_bt(MMDesc d) {
    __shared__ unsigned short As[128 * 72]; // pad 72: 2-way bank alias only
    __shared__ unsigned short Bs[128 * 72];
    int mm = blockIdx.z;
    const unsigned short* __restrict__ A = d.A[mm];
    const unsigned short* __restrict__ Bw = d.Bm[mm];
    float* __restrict__ C = d.C[mm];
    int m0 = blockIdx.x * 128, n0 = blockIdx.y * 128;
    int tid = threadIdx.x, lane = tid & 63, w = tid >> 6;
    int wm = (w & 1) * 64, wn = (w >> 1) * 64;
    int lc = lane & 15, q = lane >> 4;
    f32x4 acc[4][4];
    for (int i = 0; i < 4; ++i)
        for (int j = 0; j < 4; ++j) acc[i][j] = (f32x4){0.f, 0.f, 0.f, 0.f};
    for (int k0 = 0; k0 < UP; k0 += 64) {
        for (int i = 0; i < 4; ++i) {
            int c = i * 256 + tid;        // 1024 chunks of 8 bf16 per tile
            int row = c >> 3, kc = (c & 7) * 8;
            *(uint4*)(&As[row * 72 + kc]) = *(const uint4*)(A + (size_t)(m0 + row) * UP + k0 + kc);
            *(uint4*)(&Bs[row * 72 + kc]) = *(const uint4*)(Bw + (size_t)(n0 + row) * UP + k0 + kc);
        }
        __syncthreads();
        for (int ks = 0; ks < 64; ks += 32) {
            short8 a[4], b[4];
            for (int i = 0; i < 4; ++i)
                a[i] = *(const short8*)(&As[(wm + i * 16 + lc) * 72 + ks + q * 8]);
            for (int j = 0; j < 4; ++j)
                b[j] = *(const short8*)(&Bs[(wn + j * 16 + lc) * 72 + ks + q * 8]);
            for (int i = 0; i < 4; ++i)
                for (int j = 0; j < 4; ++j)
                    acc[i][j] = __builtin_amdgcn_mfma_f32_16x16x32_bf16(a[i], b[j], acc[i][j], 0, 0, 0);
        }
        __syncthreads();
    }
    // C/D layout: col = lane&15, row = (lane>>4)*4 + reg  [verified m89/m91]
    for (int i = 0; i < 4; ++i)
        for (int j = 0; j < 4; ++j)
            for (int r = 0; r < 4; ++r) {
                int grow = m0 + wm + i * 16 + q * 4 + r;
                int gcol = n0 + wn + j * 16 + lc;
                C[(size_t)grow * G3 + gcol] = acc[i][j][r];
            }
}

// ---------------------------------------------------------------------------
// Fused GRU gates for one diagonal's cells. mx = MXB + (l>0? PB) + bias_in,
// mh = MHB + bias_rec; z,r sigmoid; cand tanh; h = z*h + (1-z)*cand.
struct GateDesc { int lv[6]; };

__global__ void gru_gate(GateDesc gd,
                         const float* __restrict__ mxb, const float* __restrict__ mhb,
                         const float* __restrict__ pb,
                         const float* __restrict__ bias_in, const float* __restrict__ bias_rec,
                         float* __restrict__ h32, unsigned short* __restrict__ hbf) {
    int l = gd.lv[blockIdx.y];
    int f = (blockIdx.x * 256 + threadIdx.x) * 4;
    int u0 = f & 1023, b = f >> 10;
    size_t base = (size_t)l * B_ * G3 + (size_t)b * G3;
    for (int j = 0; j < 4; ++j) {
        int u = u0 + j;
        float mxz = mxb[base + u], mxr = mxb[base + 1024 + u], mxh = mxb[base + 2048 + u];
        if (l > 0) {
            mxz += pb[base + u]; mxr += pb[base + 1024 + u]; mxh += pb[base + 2048 + u];
        }
        float mhz = mhb[base + u], mhr = mhb[base + 1024 + u], mhh = mhb[base + 2048 + u];
        if (u < 1000) {
            mxz += bias_in[l * 3000 + u];
            mxr += bias_in[l * 3000 + 1000 + u];
            mxh += bias_in[l * 3000 + 2000 + u];
            mhz += bias_rec[l * 3000 + u];
            mhr += bias_rec[l * 3000 + 1000 + u];
            mhh += bias_rec[l * 3000 + 2000 + u];
        }
        float z = 1.f / (1.f + expf(-(mxz + mhz)));
        float r = 1.f / (1.f + expf(-(mxr + mhr)));
        float cand = tanhf(mxh + r * mhh);
        size_t hidx = (size_t)(l * 256 + b) * UP + u;
        float ho = h32[hidx];
        float hn = z * ho + (1.f - z) * cand;
        h32[hidx] = hn;
        hbf[hidx] = f2bf(hn);
    }
}

// Concat final hidden states -> bf16 [256][6016] (cols >= 6000 zero)
__global__ void build_final(const float* __restrict__ h32, unsigned short* __restrict__ fbf) {
    int idx = blockIdx.x * 256 + threadIdx.x; // 6016 blocks
    int b = idx / DKP, j = idx - b * DKP;
    float v = 0.f;
    if (j < DK) {
        int l = j / 1000, u = j - l * 1000;
        v = h32[(size_t)(l * 256 + b) * UP + u];
    }
    fbf[idx] = f2bf(v);
}

// Dense: logits[256][32000] = FBF[256][6016]bf16 @ dense_kernel[6000][32000]f32 + bias.
// B converted f32->bf16 in-register, LDS-transposed to K-major. BK=32, pad 56.
__launch_bounds__(256, 2)
__global__ void dense_gemm(const unsigned short* __restrict__ fbf,
                           const float* __restrict__ wd,
                           const float* __restrict__ bias,
                           float* __restrict__ out) {
    __shared__ unsigned short As[128 * 56];
    __shared__ unsigned short Bs[128 * 56];
    int m0 = blockIdx.x * 128, n0 = blockIdx.y * 128;
    int tid = threadIdx.x, lane = tid & 63, w = tid >> 6;
    int wm = (w & 1) * 64, wn = (w >> 1) * 64;
    int lc = lane & 15, q = lane >> 4;
    f32x4 acc[4][4];
    for (int i = 0; i < 4; ++i)
        for (int j = 0; j < 4; ++j) acc[i][j] = (f32x4){0.f, 0.f, 0.f, 0.f};
    for (int k0 = 0; k0 < DKP; k0 += 32) {
        for (int i = 0; i < 2; ++i) {
            int c = i * 256 + tid;        // 512 chunks
            int row = c >> 2, kc = (c & 3) * 8;
            *(uint4*)(&As[row * 56 + kc]) = *(const uint4*)(fbf + (size_t)(m0 + row) * DKP + k0 + kc);
        }
        for (int i = 0; i < 4; ++i) {
            int c = i * 256 + tid;        // 1024 float4 chunks
            int kr = c >> 5, nc = (c & 31) * 4;
            int gk = k0 + kr;
            float4 v = make_float4(0.f, 0.f, 0.f, 0.f);
            if (gk < DK) v = *(const float4*)(wd + (size_t)gk * V_ + n0 + nc);
            const float* vp = (const float*)&v;
            for (int j = 0; j < 4; ++j) Bs[(nc + j) * 56 + kr] = f2bf(vp[j]);
        }
        __syncthreads();
        short8 a[4], b[4];
        for (int i = 0; i < 4; ++i) a[i] = *(const short8*)(&As[(wm + i * 16 + lc) * 56 + q * 8]);
        for (int j = 0; j < 4; ++j) b[j] = *(const short8*)(&Bs[(wn + j * 16 + lc) * 56 + q * 8]);
        for (int i = 0; i < 4; ++i)
            for (int j = 0; j < 4; ++j)
                acc[i][j] = __builtin_amdgcn_mfma_f32_16x16x32_bf16(a[i], b[j], acc[i][j], 0, 0, 0);
        __syncthreads();
    }
    for (int i = 0; i < 4; ++i)
        for (int j = 0; j < 4; ++j)
            for (int r = 0; r < 4; ++r) {
                int grow = m0 + wm + i * 16 + q * 4 + r;
                int gcol = n0 + wn + j * 16 + lc;
                out[(size_t)grow * V_ + gcol] = acc[i][j][r] + bias[gcol];
            }
}

// In-place row softmax over [256][32000]
__global__ void softmax_rows(float* __restrict__ out) {
    __shared__ float red[256];
    int b = blockIdx.x, tid = threadIdx.x;
    float* x = out + (size_t)b * V_;
    float m = -1e30f;
    for (int i = tid; i < V_; i += 256) m = fmaxf(m, x[i]);
    red[tid] = m; __syncthreads();
    for (int s = 128; s > 0; s >>= 1) { if (tid < s) red[tid] = fmaxf(red[tid], red[tid + s]); __syncthreads(); }
    float mv = red[0];
    __syncthreads();
    float sum = 0.f;
    for (int i = tid; i < V_; i += 256) { float e = expf(x[i] - mv); x[i] = e; sum += e; }
    red[tid] = sum; __syncthreads();
    for (int s = 128; s > 0; s >>= 1) { if (tid < s) red[tid] += red[tid + s]; __syncthreads(); }
    float inv = 1.f / red[0];
    __syncthreads();
    for (int i = tid; i < V_; i += 256) x[i] *= inv;
}

// ---------------------------------------------------------------------------
extern "C" void kernel_launch(void* const* d_in, const int* in_sizes, int n_in,
                              void* d_out, int out_size, void* d_ws, size_t ws_size,
                              hipStream_t stream) {
    const int*   tokens   = (const int*)d_in[0];
    const float* init_st  = (const float*)d_in[1];
    const float* emb      = (const float*)d_in[2];
    const float* k0w      = (const float*)d_in[3];
    const float* krest    = (const float*)d_in[4];
    const float* reck     = (const float*)d_in[5];
    const float* bias_in  = (const float*)d_in[6];
    const float* bias_rec = (const float*)d_in[7];
    const float* wd       = (const float*)d_in[8];
    const float* bd       = (const float*)d_in[9];
    float* out = (float*)d_out;
    (void)in_sizes; (void)n_in; (void)out_size; (void)ws_size;

    // workspace layout (bytes), total ~176 MB
    char* ws = (char*)d_ws;
    unsigned short* WTS = (unsigned short*)(ws);                 // 106,954,752
    unsigned short* XBF = (unsigned short*)(ws + 106954752);     //   7,864,320
    float*          H32 = (float*)        (ws + 114819072);     //   6,291,456
    unsigned short* HBF = (unsigned short*)(ws + 121110528);    //   3,145,728
    float*          MXB = (float*)        (ws + 124256256);     //  18,874,368
    float*          MHB = (float*)        (ws + 143130624);     //  18,874,368
    float*          PB  = (float*)        (ws + 162004992);     //  18,874,368
    unsigned short* FBF = (unsigned short*)(ws + 180879360);    //   3,080,192

    conv_weights<<<dim3(48, 16, 17), 256, 0, stream>>>(k0w, krest, reck, WTS);
    emb_gather<<<dim3(3840), 256, 0, stream>>>(tokens, emb, XBF);
    h_init<<<dim3(1536), 256, 0, stream>>>(init_st, H32, HBF);

    // anti-diagonal wavefront over (t, l): 20 steps
    for (int d = 0; d < T_ + L_ - 1; ++d) {
        MMDesc md;
        GateDesc gd;
        int nmm = 0, nc = 0;
        int lmin = (d - (T_ - 1) > 0) ? d - (T_ - 1) : 0;
        int lmax = (d < L_ - 1) ? d : L_ - 1;
        for (int l = lmin; l <= lmax; ++l) {
            int t = d - l;
            // x-projection: MXB[l] = x_t @ WX[l]
            md.A[nmm] = XBF + (size_t)t * B_ * E_;
            md.Bm[nmm] = WTS + (size_t)l * MATSZ;
            md.C[nmm] = MXB + (size_t)l * B_ * G3; nmm++;
            // recurrent: MHB[l] = h_l(t-1) @ WR[l]
            md.A[nmm] = HBF + (size_t)l * B_ * UP;
            md.Bm[nmm] = WTS + (size_t)(11 + l) * MATSZ;
            md.C[nmm] = MHB + (size_t)l * B_ * G3; nmm++;
            // skip: PB[l] = h_{l-1}(t) @ WP[l]
            if (l > 0) {
                md.A[nmm] = HBF + (size_t)(l - 1) * B_ * UP;
                md.Bm[nmm] = WTS + (size_t)(5 + l) * MATSZ;
                md.C[nmm] = PB + (size_t)l * B_ * G3; nmm++;
            }
            gd.lv[nc++] = l;
        }
        gemm_bt<<<dim3(2, 24, nmm), 256, 0, stream>>>(md);
        gru_gate<<<dim3(256, nc), 256, 0, stream>>>(gd, MXB, MHB, PB, bias_in, bias_rec, H32, HBF);
    }

    build_final<<<dim3(6016), 256, 0, stream>>>(H32, FBF);
    dense_gemm<<<dim3(2, 250), 256, 0, stream>>>(FBF, wd, bd, out);
    softmax_rows<<<dim3(256), 256, 0, stream>>>(out);
}